// Round 19
// baseline (279.107 us; speedup 1.0000x reference)
//
#include <hip/hip_runtime.h>
#include <hip/hip_bf16.h>

// Problem constants (match reference setup_inputs)
static constexpr int N = 100000;
static constexpr int E = 600000;
static constexpr int D = 128;
static constexpr int B = 10000;
static constexpr int C = 32;
static constexpr int NB = (N + 1023) / 1024;   // 98 scan chunks per N-array
static constexpr int TOUCHB = (N * (D / 4) + 255) / 256;   // 12500 float4-touch blocks

typedef __attribute__((ext_vector_type(8))) short short8;   // 8 bf16 (4 VGPRs)
typedef __attribute__((ext_vector_type(4))) float f32x4;    // MFMA acc

// bf16 RNE helpers (bit-level, no NaN inputs here)
static __device__ __forceinline__ unsigned short f2bf(float f) {
    unsigned u = __float_as_uint(f);
    unsigned r = (u + 0x7FFFu + ((u >> 16) & 1u)) >> 16;
    return (unsigned short)r;
}
static __device__ __forceinline__ float bf2f(unsigned short h) {
    return __uint_as_float(((unsigned)h) << 16);
}

// split 8 consecutive floats into hi/lo bf16 fragments
static __device__ __forceinline__ void split8(const float4 v0, const float4 v1,
                                              short8& h, short8& l) {
    const float f[8] = {v0.x, v0.y, v0.z, v0.w, v1.x, v1.y, v1.z, v1.w};
    #pragma unroll
    for (int i = 0; i < 8; ++i) {
        unsigned short hh = f2bf(f[i]);
        h[i] = (short)hh;
        l[i] = (short)f2bf(f[i] - bf2f(hh));
    }
}

// ---------------- label marking ----------------
__global__ void lab_k(const int* __restrict__ label_pos, int* __restrict__ labflag,
                      int* __restrict__ flag, int nlab) {
    int i = blockIdx.x * blockDim.x + threadIdx.x;
    if (i < nlab) {
        int v = label_pos[i];
        labflag[v] = 1;
        flag[v] = 1;   // labels are in U
    }
}

// ---------------- merged edge pass (deg + U-mark) + weight swizzle + L3 touch ----------------
// blocks [0, EB): per-edge deg atomic + flag[src]=1 where dst is a label.
// blocks [EB, EB+64): swizzle fp32 W[128][128] -> MFMA-B fragment order, hi/lo bf16:
//   out[plane][((ko*8+no)*64+lane)*8+j] = W[ko*32+(lane>>4)*8+j][no*16+(lane&15)]
// blocks [EB+64, EB+64+TOUCHB): stream node_state into L3.
__global__ __launch_bounds__(256) void deg_swz_k(
    const int* __restrict__ src, const int* __restrict__ dst,
    const int* __restrict__ labflag,
    int* __restrict__ deg, int* __restrict__ flag, int nE, int EB,
    const float* W0, const float* W1, const float* W2, const float* W3,
    unsigned short* __restrict__ out,
    const float* __restrict__ xtouch, float* __restrict__ sink) {
    if ((int)blockIdx.x < EB) {
        int e = blockIdx.x * 256 + threadIdx.x;
        if (e < nE) {
            int d = dst[e];
            atomicAdd(&deg[d], 1);
            if (labflag[d]) flag[src[e]] = 1;   // benign race, all write 1
        }
        return;
    }
    if ((int)blockIdx.x < EB + 64) {
        const int sb = blockIdx.x - EB;          // 0..63
        const int m = sb >> 4;
        const int chunk = sb & 15;
        const float* W = (m == 0) ? W0 : (m == 1) ? W1 : (m == 2) ? W2 : W3;
        unsigned short* o = out + (size_t)m * 32768;
        #pragma unroll
        for (int it = 0; it < 4; ++it) {
            int f = chunk * 1024 + it * 256 + threadIdx.x;   // 0..16383
            int j = f & 7;
            int lane = (f >> 3) & 63;
            int fi = f >> 9;                                 // ko*8+no
            int k = (fi >> 3) * 32 + (lane >> 4) * 8 + j;
            int n = (fi & 7) * 16 + (lane & 15);
            float a = W[k * 128 + n];
            unsigned short h = f2bf(a);
            o[f] = h;
            o[16384 + f] = f2bf(a - bf2f(h));
        }
        return;
    }
    // ---- L3 warm touch of node_state
    const int f4 = (blockIdx.x - (EB + 64)) * 256 + threadIdx.x;
    if (f4 < N * (D / 4)) {
        float4 v = reinterpret_cast<const float4*>(xtouch)[f4];
        float s = v.x + v.y + v.z + v.w;
        if (s > 1e30f) *sink = s;   // data-dependent, never taken: keeps the loads
    }
}

// ---------------- single-dispatch scan (merges scan1m+scan3m) ----------------
// blocks [0,NB): deg -> roff/cur.  blocks [NB,2NB): flag -> map/ulist.
// Each block computes its own offset by directly summing its PREFIX chunks
// (prefix chunks 0..bloc-1 are always full 1024-elem chunks since bloc<=NB-1
// and (NB-1)*1024 <= N — no boundary logic, the r8/r16 trap is absent).
// deg total == E by construction (block 0 writes it as a constant);
// flag total written by the LAST flag block (its prefix + own-chunk total).
__global__ __launch_bounds__(256) void scan_k(
    const int* __restrict__ deg, const int* __restrict__ flag,
    int* __restrict__ roff, int* __restrict__ cur,
    int* __restrict__ map, int* __restrict__ ulist, int* __restrict__ ucnt,
    int n)
{
    __shared__ int csum[128];
    __shared__ int lsum[256];
    const int t = threadIdx.x;
    const bool isdeg = (int)blockIdx.x < NB;
    const int bloc = isdeg ? blockIdx.x : blockIdx.x - NB;
    const int* v = isdeg ? deg : flag;

    // ---- prefix-chunk sums: thread t sums full chunk t (t < bloc)
    if (t < 128) csum[t] = 0;
    __syncthreads();
    if (t < bloc) {
        const int4* p = reinterpret_cast<const int4*>(v + t * 1024);
        int s = 0;
        #pragma unroll 8
        for (int i = 0; i < 256; ++i) {
            int4 x = p[i];
            s += x.x + x.y + x.z + x.w;
        }
        csum[t] = s;
    }
    __syncthreads();
    for (int off = 64; off > 0; off >>= 1) {
        if (t < off) csum[t] += csum[t + off];
        __syncthreads();
    }
    const int boff = csum[0];

    if (isdeg && bloc == 0 && t == 0) roff[n] = E;   // deg total == E

    // ---- own-chunk inclusive scan (identical to the proven scan3 body)
    const int base = bloc * 1024 + t * 4;
    int d[4];
    int s = 0;
    #pragma unroll
    for (int i = 0; i < 4; ++i) {
        int idx = base + i;
        d[i] = (idx < n) ? v[idx] : 0;
        s += d[i];
    }
    lsum[t] = s;
    __syncthreads();
    for (int off = 1; off < 256; off <<= 1) {
        int u = (t >= off) ? lsum[t - off] : 0;
        __syncthreads();
        lsum[t] += u;
        __syncthreads();
    }
    if (!isdeg && bloc == NB - 1 && t == 255) *ucnt = boff + lsum[255];

    int run = boff + lsum[t] - s;
    #pragma unroll
    for (int i = 0; i < 4; ++i) {
        int idx = base + i;
        if (idx < n) {
            if (isdeg) {
                roff[idx] = run;
                cur[idx]  = run;
                run += d[i];
            } else if (d[i]) {
                map[idx] = run;
                ulist[run] = idx;
                ++run;
            }
        }
    }
}

__global__ void fill_k(const int* __restrict__ src, const int* __restrict__ dst,
                       int* __restrict__ cur, int* __restrict__ csr_src, int nE) {
    int e = blockIdx.x * blockDim.x + threadIdx.x;
    if (e < nE) {
        int p = atomicAdd(&cur[dst[e]], 1);
        csr_src[p] = src[e];
    }
}

// ---------------- gather-mean aggregation (r12 v1: measured best) ----------------
template <bool GATHER, bool MAP>
__global__ __launch_bounds__(256) void gather_mean_k(
    const float* __restrict__ x, const int* __restrict__ roff,
    const int* __restrict__ csr_src, const int* __restrict__ rows,
    const int* __restrict__ map, const int* __restrict__ nrows_ptr,
    float* __restrict__ out, int nrows_max) {
    const int nrows = nrows_ptr ? nrows_ptr[0] : nrows_max;
    const int w = blockIdx.x * (blockDim.x >> 6) + (threadIdx.x >> 6);
    if (w >= nrows) return;
    const int lane = threadIdx.x & 63;
    const int n  = GATHER ? rows[w] : w;
    const int jb = roff[n];
    const int je = roff[n + 1];
    const float* xb = x + lane * 2;

    float ax = 0.f, ay = 0.f;
    int j = jb;
    for (; j + 4 <= je; j += 4) {
        int s0 = csr_src[j + 0];
        int s1 = csr_src[j + 1];
        int s2 = csr_src[j + 2];
        int s3 = csr_src[j + 3];
        if (MAP) { s0 = map[s0]; s1 = map[s1]; s2 = map[s2]; s3 = map[s3]; }
        float2 v0 = *reinterpret_cast<const float2*>(xb + (size_t)s0 * D);
        float2 v1 = *reinterpret_cast<const float2*>(xb + (size_t)s1 * D);
        float2 v2 = *reinterpret_cast<const float2*>(xb + (size_t)s2 * D);
        float2 v3 = *reinterpret_cast<const float2*>(xb + (size_t)s3 * D);
        ax += v0.x + v1.x + v2.x + v3.x;
        ay += v0.y + v1.y + v2.y + v3.y;
    }
    for (; j < je; ++j) {
        int s = csr_src[j];
        if (MAP) s = map[s];
        float2 v = *reinterpret_cast<const float2*>(xb + (size_t)s * D);
        ax += v.x;
        ay += v.y;
    }
    const float inv = 1.0f / fmaxf((float)(je - jb), 1.0f);
    *reinterpret_cast<float2*>(out + (size_t)w * D + lane * 2) =
        make_float2(ax * inv, ay * inv);
}

// ---------------- SAGE layer 1, split-bf16 MFMA, LDS-free / barrier-free ----------------
// 32-row blocks, 4 waves = {row-half} x {col-half}; each wave 16 rows x 64 cols.
template <bool GATHER, bool MAP>
__global__ __launch_bounds__(256, 6) void sage_mfma_k(
    const float* __restrict__ mean, const float* __restrict__ xsrc,
    const int* __restrict__ rows, const int* __restrict__ map,
    const int* __restrict__ nrows_ptr,
    const unsigned short* __restrict__ WlSw, const unsigned short* __restrict__ WrSw,
    const float* __restrict__ bl, float* __restrict__ xout, int nrows_max)
{
    const int nrows = nrows_ptr ? nrows_ptr[0] : nrows_max;
    const int rb = blockIdx.x * 32;
    if (rb >= nrows) return;

    const int t = threadIdx.x;
    const int wrow = (t >> 6) & 1;
    const int wcol = t >> 7;
    const int lane = t & 63;
    const int mcol = lane & 15;
    const int q = lane >> 4;
    const int r = rb + wrow * 16 + mcol;

    f32x4 acc[4];
    #pragma unroll
    for (int no = 0; no < 4; ++no) acc[no] = (f32x4){0.f, 0.f, 0.f, 0.f};

    size_t gidx = 0;
    if (r < nrows) {
        int g = GATHER ? rows[r] : r;
        if (MAP) g = map[g];
        gidx = (size_t)g;
    }

    #pragma unroll
    for (int br = 0; br < 2; ++br) {
        const unsigned short* __restrict__ Wm = br ? WrSw : WlSw;
        #pragma unroll
        for (int kp = 0; kp < 4; ++kp) {
            short8 aH, aL;
            {
                float4 v0 = make_float4(0.f, 0.f, 0.f, 0.f);
                float4 v1 = make_float4(0.f, 0.f, 0.f, 0.f);
                if (r < nrows) {
                    const float* p = (br == 0)
                        ? mean + (size_t)r * D + kp * 32 + q * 8
                        : xsrc + gidx * D + kp * 32 + q * 8;
                    v0 = *reinterpret_cast<const float4*>(p);
                    v1 = *reinterpret_cast<const float4*>(p + 4);
                }
                split8(v0, v1, aH, aL);
            }
            #pragma unroll
            for (int no = 0; no < 4; ++no) {
                const size_t fo = ((size_t)(kp * 8 + wcol * 4 + no) * 64 + lane) * 8;
                short8 bh = *reinterpret_cast<const short8*>(Wm + fo);
                short8 bo = *reinterpret_cast<const short8*>(Wm + 16384 + fo);
                acc[no] = __builtin_amdgcn_mfma_f32_16x16x32_bf16(aH, bh, acc[no], 0, 0, 0);
                acc[no] = __builtin_amdgcn_mfma_f32_16x16x32_bf16(aL, bh, acc[no], 0, 0, 0);
                acc[no] = __builtin_amdgcn_mfma_f32_16x16x32_bf16(aH, bo, acc[no], 0, 0, 0);
            }
        }
    }

    #pragma unroll
    for (int no = 0; no < 4; ++no) {
        const int col = wcol * 64 + no * 16 + mcol;
        const float bias = bl[col];
        #pragma unroll
        for (int ri = 0; ri < 4; ++ri) {
            const int row = rb + wrow * 16 + q * 4 + ri;
            if (row < nrows)
                xout[(size_t)row * D + col] = fmaxf(acc[no][ri] + bias, 0.f);
        }
    }
}

// ---------------- fused layer-2 + classifier ----------------
__global__ __launch_bounds__(256) void sage2_cls_k(
    const float* __restrict__ mean, const float* __restrict__ x1c,
    const int* __restrict__ label_pos, const int* __restrict__ map,
    const unsigned short* __restrict__ WlSw, const unsigned short* __restrict__ WrSw,
    const float* __restrict__ bl,
    const float* __restrict__ Wc1, const float* __restrict__ bc1,
    const float* __restrict__ Wc2, const float* __restrict__ bc2,
    float* __restrict__ out, int nrows)
{
    __shared__ float Xs[32][132];
    __shared__ float Hs[32][128];
    const int rb = blockIdx.x * 32;
    const int t = threadIdx.x;
    const int wrow = (t >> 6) & 1;
    const int wcol = t >> 7;
    const int lane = t & 63;
    const int mcol = lane & 15;
    const int q = lane >> 4;
    const int r = rb + wrow * 16 + mcol;

    f32x4 acc[4];
    #pragma unroll
    for (int no = 0; no < 4; ++no) acc[no] = (f32x4){0.f, 0.f, 0.f, 0.f};

    size_t gidx = 0;
    if (r < nrows) gidx = (size_t)map[label_pos[r]];

    #pragma unroll
    for (int br = 0; br < 2; ++br) {
        const unsigned short* __restrict__ Wm = br ? WrSw : WlSw;
        #pragma unroll
        for (int kp = 0; kp < 4; ++kp) {
            short8 aH, aL;
            {
                float4 v0 = make_float4(0.f, 0.f, 0.f, 0.f);
                float4 v1 = make_float4(0.f, 0.f, 0.f, 0.f);
                if (r < nrows) {
                    const float* p = (br == 0)
                        ? mean + (size_t)r * D + kp * 32 + q * 8
                        : x1c + gidx * D + kp * 32 + q * 8;
                    v0 = *reinterpret_cast<const float4*>(p);
                    v1 = *reinterpret_cast<const float4*>(p + 4);
                }
                split8(v0, v1, aH, aL);
            }
            #pragma unroll
            for (int no = 0; no < 4; ++no) {
                const size_t fo = ((size_t)(kp * 8 + wcol * 4 + no) * 64 + lane) * 8;
                short8 bh = *reinterpret_cast<const short8*>(Wm + fo);
                short8 bo = *reinterpret_cast<const short8*>(Wm + 16384 + fo);
                acc[no] = __builtin_amdgcn_mfma_f32_16x16x32_bf16(aH, bh, acc[no], 0, 0, 0);
                acc[no] = __builtin_amdgcn_mfma_f32_16x16x32_bf16(aL, bh, acc[no], 0, 0, 0);
                acc[no] = __builtin_amdgcn_mfma_f32_16x16x32_bf16(aH, bo, acc[no], 0, 0, 0);
            }
        }
    }

    #pragma unroll
    for (int no = 0; no < 4; ++no) {
        const int col = wcol * 64 + no * 16 + mcol;
        const float bias = bl[col];
        #pragma unroll
        for (int ri = 0; ri < 4; ++ri) {
            const int lrow = wrow * 16 + q * 4 + ri;
            Xs[lrow][col] = fmaxf(acc[no][ri] + bias, 0.f);
        }
    }
    __syncthreads();

    {
        const int col  = t & 127;
        const int half = t >> 7;
        float a2[16];
        const float bias = bc1[col];
        #pragma unroll
        for (int i = 0; i < 16; ++i) a2[i] = bias;
        for (int k = 0; k < 128; ++k) {
            float w = Wc1[k * 128 + col];
            #pragma unroll
            for (int i = 0; i < 16; ++i)
                a2[i] = fmaf(Xs[half * 16 + i][k], w, a2[i]);
        }
        #pragma unroll
        for (int i = 0; i < 16; ++i)
            Hs[half * 16 + i][col] = fmaxf(a2[i], 0.0f);
    }
    __syncthreads();

    {
        const int c  = t & 31;
        const int rg = t >> 5;
        float o[4];
        const float b2 = bc2[c];
        #pragma unroll
        for (int i = 0; i < 4; ++i) o[i] = b2;
        for (int k = 0; k < 128; ++k) {
            float w = Wc2[k * 32 + c];
            #pragma unroll
            for (int i = 0; i < 4; ++i)
                o[i] = fmaf(Hs[rg + 8 * i][k], w, o[i]);
        }
        #pragma unroll
        for (int i = 0; i < 4; ++i) {
            int row = rb + rg + 8 * i;
            if (row < nrows) out[(size_t)row * C + c] = o[i];
        }
    }
}

// ---------------- launch ----------------

extern "C" void kernel_launch(void* const* d_in, const int* in_sizes, int n_in,
                              void* d_out, int out_size, void* d_ws, size_t ws_size,
                              hipStream_t stream) {
    const float* node_state = (const float*)d_in[0];
    const int*   edge_index = (const int*)d_in[1];
    const int*   label_pos  = (const int*)d_in[2];
    const float* W1l = (const float*)d_in[3];
    const float* b1l = (const float*)d_in[4];
    const float* W1r = (const float*)d_in[5];
    const float* W2l = (const float*)d_in[6];
    const float* b2l = (const float*)d_in[7];
    const float* W2r = (const float*)d_in[8];
    const float* Wc1 = (const float*)d_in[9];
    const float* bc1 = (const float*)d_in[10];
    const float* Wc2 = (const float*)d_in[11];
    const float* bc2 = (const float*)d_in[12];
    float* out = (float*)d_out;

    const int* src = edge_index;       // edge_index[0]
    const int* dst = edge_index + E;   // edge_index[1]

    // workspace layout (floats first for alignment)
    char* ws = (char*)d_ws;
    float* x1c   = (float*)ws;                    ws += sizeof(float) * (size_t)N * D;
    float* bufA  = (float*)ws;                    ws += sizeof(float) * (size_t)N * D;
    unsigned short* Wsw = (unsigned short*)ws;    ws += sizeof(unsigned short) * 4 * 32768;
    int* deg     = (int*)ws;                      ws += sizeof(int) * N;   // |
    int* flag    = (int*)ws;                      ws += sizeof(int) * N;   // | contiguous: one
    int* labflag = (int*)ws;                      ws += sizeof(int) * N;   // | memset
    int* ucnt    = (int*)ws;                      ws += sizeof(int);       // |
    float* sink  = (float*)ws;                    ws += sizeof(float);
    ws += sizeof(int) * 2;                        // pad to 16B
    int* roff    = (int*)ws;                      ws += sizeof(int) * (N + 1);
    int* cur     = (int*)ws;                      ws += sizeof(int) * N;
    int* csr_src = (int*)ws;                      ws += sizeof(int) * E;
    int* map     = (int*)ws;                      ws += sizeof(int) * N;
    int* ulist   = (int*)ws;                      ws += sizeof(int) * N;
    // bufA: mean1c [ucnt][D]; then mean2g [B][D]
    float* mean1c = bufA;
    float* mean2g = bufA;

    const int TB = 256;
    const int EB = (E + TB - 1) / TB;   // 2344 edge blocks

    // ---- preprocessing: 4 dispatches + 1 memset ----
    hipMemsetAsync(deg, 0, sizeof(int) * (3 * N + 1), stream);  // deg,flag,labflag,ucnt
    lab_k<<<(B + TB - 1) / TB, TB, 0, stream>>>(label_pos, labflag, flag, B);
    deg_swz_k<<<EB + 64 + TOUCHB, TB, 0, stream>>>(src, dst, labflag, deg, flag, E, EB,
                                                   W1l, W1r, W2l, W2r, Wsw,
                                                   node_state, sink);
    scan_k<<<2 * NB, 256, 0, stream>>>(deg, flag, roff, cur, map, ulist, ucnt, N);
    fill_k<<<EB, TB, 0, stream>>>(src, dst, cur, csr_src, E);

    // ---- layer 1: only U rows (compact outputs) ----
    gather_mean_k<true, false><<<(N + 3) / 4, TB, 0, stream>>>(
        node_state, roff, csr_src, ulist, nullptr, ucnt, mean1c, N);
    sage_mfma_k<true, false><<<(N + 31) / 32, TB, 0, stream>>>(
        mean1c, node_state, ulist, nullptr, ucnt,
        Wsw, Wsw + 32768, b1l, x1c, N);

    // ---- layer 2 + classifier (fused; label rows) ----
    gather_mean_k<true, true><<<(B + 3) / 4, TB, 0, stream>>>(
        x1c, roff, csr_src, label_pos, map, nullptr, mean2g, B);
    sage2_cls_k<<<(B + 31) / 32, TB, 0, stream>>>(
        mean2g, x1c, label_pos, map,
        Wsw + 65536, Wsw + 98304, b2l,
        Wc1, bc1, Wc2, bc2, out, B);
}

// Round 20
// 267.387 us; speedup vs baseline: 1.0438x; 1.0438x over previous
//
#include <hip/hip_runtime.h>
#include <hip/hip_bf16.h>

// Problem constants (match reference setup_inputs)
static constexpr int N = 100000;
static constexpr int E = 600000;
static constexpr int D = 128;
static constexpr int B = 10000;
static constexpr int C = 32;
static constexpr int NB = (N + 1023) / 1024;   // 98 scan chunks per N-array
static constexpr int TOUCHB = (N * (D / 4) + 255) / 256;   // 12500 float4-touch blocks

typedef __attribute__((ext_vector_type(8))) short short8;   // 8 bf16 (4 VGPRs)
typedef __attribute__((ext_vector_type(4))) float f32x4;    // MFMA acc

// bf16 RNE helpers (bit-level, no NaN inputs here)
static __device__ __forceinline__ unsigned short f2bf(float f) {
    unsigned u = __float_as_uint(f);
    unsigned r = (u + 0x7FFFu + ((u >> 16) & 1u)) >> 16;
    return (unsigned short)r;
}
static __device__ __forceinline__ float bf2f(unsigned short h) {
    return __uint_as_float(((unsigned)h) << 16);
}

// split 8 consecutive floats into hi/lo bf16 fragments
static __device__ __forceinline__ void split8(const float4 v0, const float4 v1,
                                              short8& h, short8& l) {
    const float f[8] = {v0.x, v0.y, v0.z, v0.w, v1.x, v1.y, v1.z, v1.w};
    #pragma unroll
    for (int i = 0; i < 8; ++i) {
        unsigned short hh = f2bf(f[i]);
        h[i] = (short)hh;
        l[i] = (short)f2bf(f[i] - bf2f(hh));
    }
}

// ---------------- label marking ----------------
__global__ void lab_k(const int* __restrict__ label_pos, int* __restrict__ labflag,
                      int* __restrict__ flag, int nlab) {
    int i = blockIdx.x * blockDim.x + threadIdx.x;
    if (i < nlab) {
        int v = label_pos[i];
        labflag[v] = 1;
        flag[v] = 1;   // labels are in U
    }
}

// ---------------- merged edge pass (deg + U-mark) + weight swizzle + L3 touch ----------------
// blocks [0, EB): per-edge deg atomic + flag[src]=1 where dst is a label.
// blocks [EB, EB+64): swizzle fp32 W[128][128] -> MFMA-B fragment order, hi/lo bf16:
//   out[plane][((ko*8+no)*64+lane)*8+j] = W[ko*32+(lane>>4)*8+j][no*16+(lane&15)]
// blocks [EB+64, EB+64+TOUCHB): stream node_state into L3.
__global__ __launch_bounds__(256) void deg_swz_k(
    const int* __restrict__ src, const int* __restrict__ dst,
    const int* __restrict__ labflag,
    int* __restrict__ deg, int* __restrict__ flag, int nE, int EB,
    const float* W0, const float* W1, const float* W2, const float* W3,
    unsigned short* __restrict__ out,
    const float* __restrict__ xtouch, float* __restrict__ sink) {
    if ((int)blockIdx.x < EB) {
        int e = blockIdx.x * 256 + threadIdx.x;
        if (e < nE) {
            int d = dst[e];
            atomicAdd(&deg[d], 1);
            if (labflag[d]) flag[src[e]] = 1;   // benign race, all write 1
        }
        return;
    }
    if ((int)blockIdx.x < EB + 64) {
        const int sb = blockIdx.x - EB;          // 0..63
        const int m = sb >> 4;
        const int chunk = sb & 15;
        const float* W = (m == 0) ? W0 : (m == 1) ? W1 : (m == 2) ? W2 : W3;
        unsigned short* o = out + (size_t)m * 32768;
        #pragma unroll
        for (int it = 0; it < 4; ++it) {
            int f = chunk * 1024 + it * 256 + threadIdx.x;   // 0..16383
            int j = f & 7;
            int lane = (f >> 3) & 63;
            int fi = f >> 9;                                 // ko*8+no
            int k = (fi >> 3) * 32 + (lane >> 4) * 8 + j;
            int n = (fi & 7) * 16 + (lane & 15);
            float a = W[k * 128 + n];
            unsigned short h = f2bf(a);
            o[f] = h;
            o[16384 + f] = f2bf(a - bf2f(h));
        }
        return;
    }
    // ---- L3 warm touch of node_state
    const int f4 = (blockIdx.x - (EB + 64)) * 256 + threadIdx.x;
    if (f4 < N * (D / 4)) {
        float4 v = reinterpret_cast<const float4*>(xtouch)[f4];
        float s = v.x + v.y + v.z + v.w;
        if (s > 1e30f) *sink = s;   // data-dependent, never taken: keeps the loads
    }
}

// merged chunk sums with PER-ARRAY-ALIGNED chunking (the r8/r16 crash was
// scanning [deg|flag] as contiguous 2N: chunk 97 straddles the boundary since
// N % 1024 != 0). blocks [0,NB) sum deg chunks; [NB,2NB) sum flag chunks.
__global__ __launch_bounds__(256) void scan1m_k(const int* __restrict__ deg,
                                                const int* __restrict__ flag,
                                                int* __restrict__ bsum, int n) {
    __shared__ int lsum[256];
    const int t = threadIdx.x;
    const bool isdeg = (int)blockIdx.x < NB;
    const int bloc = isdeg ? blockIdx.x : blockIdx.x - NB;
    const int* v = isdeg ? deg : flag;
    const int base = bloc * 1024 + t * 4;
    int s = 0;
    #pragma unroll
    for (int i = 0; i < 4; ++i) {
        int idx = base + i;
        if (idx < n) s += v[idx];
    }
    lsum[t] = s;
    __syncthreads();
    for (int off = 128; off > 0; off >>= 1) {
        if (t < off) lsum[t] += lsum[t + off];
        __syncthreads();
    }
    if (t == 0) bsum[blockIdx.x] = lsum[0];
}

// merged phase 3, fully independent groups:
// blocks [0,NB):    local scan of bsum[0..NB)   -> roff/cur from deg; block 0 writes roff[N]
// blocks [NB,2NB):  local scan of bsum[NB..2NB) -> map/ulist from flag; its block 0 writes ucnt
__global__ __launch_bounds__(256) void scan3m_k(
    const int* __restrict__ deg, const int* __restrict__ flag,
    const int* __restrict__ bsum,
    int* __restrict__ roff, int* __restrict__ cur,
    int* __restrict__ map, int* __restrict__ ulist, int* __restrict__ ucnt,
    int n)
{
    __shared__ int sb[128];
    __shared__ int lsum[256];
    const int t = threadIdx.x;
    const bool isdeg = (int)blockIdx.x < NB;
    const int bloc = isdeg ? blockIdx.x : blockIdx.x - NB;
    const int* bs = isdeg ? bsum : bsum + NB;
    const int* v  = isdeg ? deg : flag;

    // local inclusive scan of this group's NB chunk sums
    if (t < 128) sb[t] = (t < NB) ? bs[t] : 0;
    __syncthreads();
    for (int off = 1; off < 128; off <<= 1) {
        int u = (t < 128 && t >= off) ? sb[t - off] : 0;
        __syncthreads();
        if (t < 128) sb[t] += u;
        __syncthreads();
    }
    const int boff = (bloc == 0) ? 0 : sb[bloc - 1];
    if (bloc == 0 && t == 0) {
        if (isdeg) roff[n] = sb[NB - 1];   // == E
        else *ucnt = sb[NB - 1];
    }

    const int base = bloc * 1024 + t * 4;
    int d[4];
    int s = 0;
    #pragma unroll
    for (int i = 0; i < 4; ++i) {
        int idx = base + i;
        d[i] = (idx < n) ? v[idx] : 0;
        s += d[i];
    }
    lsum[t] = s;
    __syncthreads();
    for (int off = 1; off < 256; off <<= 1) {
        int u = (t >= off) ? lsum[t - off] : 0;
        __syncthreads();
        lsum[t] += u;
        __syncthreads();
    }
    int run = boff + lsum[t] - s;
    #pragma unroll
    for (int i = 0; i < 4; ++i) {
        int idx = base + i;
        if (idx < n) {
            if (isdeg) {
                roff[idx] = run;
                cur[idx]  = run;
                run += d[i];
            } else if (d[i]) {
                map[idx] = run;
                ulist[run] = idx;
                ++run;
            }
        }
    }
}

__global__ void fill_k(const int* __restrict__ src, const int* __restrict__ dst,
                       int* __restrict__ cur, int* __restrict__ csr_src, int nE) {
    int e = blockIdx.x * blockDim.x + threadIdx.x;
    if (e < nE) {
        int p = atomicAdd(&cur[dst[e]], 1);
        csr_src[p] = src[e];
    }
}

// ---------------- gather-mean aggregation (r12 v1: measured best) ----------------
template <bool GATHER, bool MAP>
__global__ __launch_bounds__(256) void gather_mean_k(
    const float* __restrict__ x, const int* __restrict__ roff,
    const int* __restrict__ csr_src, const int* __restrict__ rows,
    const int* __restrict__ map, const int* __restrict__ nrows_ptr,
    float* __restrict__ out, int nrows_max) {
    const int nrows = nrows_ptr ? nrows_ptr[0] : nrows_max;
    const int w = blockIdx.x * (blockDim.x >> 6) + (threadIdx.x >> 6);
    if (w >= nrows) return;
    const int lane = threadIdx.x & 63;
    const int n  = GATHER ? rows[w] : w;
    const int jb = roff[n];
    const int je = roff[n + 1];
    const float* xb = x + lane * 2;

    float ax = 0.f, ay = 0.f;
    int j = jb;
    for (; j + 4 <= je; j += 4) {
        int s0 = csr_src[j + 0];
        int s1 = csr_src[j + 1];
        int s2 = csr_src[j + 2];
        int s3 = csr_src[j + 3];
        if (MAP) { s0 = map[s0]; s1 = map[s1]; s2 = map[s2]; s3 = map[s3]; }
        float2 v0 = *reinterpret_cast<const float2*>(xb + (size_t)s0 * D);
        float2 v1 = *reinterpret_cast<const float2*>(xb + (size_t)s1 * D);
        float2 v2 = *reinterpret_cast<const float2*>(xb + (size_t)s2 * D);
        float2 v3 = *reinterpret_cast<const float2*>(xb + (size_t)s3 * D);
        ax += v0.x + v1.x + v2.x + v3.x;
        ay += v0.y + v1.y + v2.y + v3.y;
    }
    for (; j < je; ++j) {
        int s = csr_src[j];
        if (MAP) s = map[s];
        float2 v = *reinterpret_cast<const float2*>(xb + (size_t)s * D);
        ax += v.x;
        ay += v.y;
    }
    const float inv = 1.0f / fmaxf((float)(je - jb), 1.0f);
    *reinterpret_cast<float2*>(out + (size_t)w * D + lane * 2) =
        make_float2(ax * inv, ay * inv);
}

// ---------------- SAGE layer 1, split-bf16 MFMA, LDS-free / barrier-free ----------------
// 32-row blocks, 4 waves = {row-half} x {col-half}; each wave 16 rows x 64 cols.
template <bool GATHER, bool MAP>
__global__ __launch_bounds__(256, 6) void sage_mfma_k(
    const float* __restrict__ mean, const float* __restrict__ xsrc,
    const int* __restrict__ rows, const int* __restrict__ map,
    const int* __restrict__ nrows_ptr,
    const unsigned short* __restrict__ WlSw, const unsigned short* __restrict__ WrSw,
    const float* __restrict__ bl, float* __restrict__ xout, int nrows_max)
{
    const int nrows = nrows_ptr ? nrows_ptr[0] : nrows_max;
    const int rb = blockIdx.x * 32;
    if (rb >= nrows) return;

    const int t = threadIdx.x;
    const int wrow = (t >> 6) & 1;
    const int wcol = t >> 7;
    const int lane = t & 63;
    const int mcol = lane & 15;
    const int q = lane >> 4;
    const int r = rb + wrow * 16 + mcol;

    f32x4 acc[4];
    #pragma unroll
    for (int no = 0; no < 4; ++no) acc[no] = (f32x4){0.f, 0.f, 0.f, 0.f};

    size_t gidx = 0;
    if (r < nrows) {
        int g = GATHER ? rows[r] : r;
        if (MAP) g = map[g];
        gidx = (size_t)g;
    }

    #pragma unroll
    for (int br = 0; br < 2; ++br) {
        const unsigned short* __restrict__ Wm = br ? WrSw : WlSw;
        #pragma unroll
        for (int kp = 0; kp < 4; ++kp) {
            short8 aH, aL;
            {
                float4 v0 = make_float4(0.f, 0.f, 0.f, 0.f);
                float4 v1 = make_float4(0.f, 0.f, 0.f, 0.f);
                if (r < nrows) {
                    const float* p = (br == 0)
                        ? mean + (size_t)r * D + kp * 32 + q * 8
                        : xsrc + gidx * D + kp * 32 + q * 8;
                    v0 = *reinterpret_cast<const float4*>(p);
                    v1 = *reinterpret_cast<const float4*>(p + 4);
                }
                split8(v0, v1, aH, aL);
            }
            #pragma unroll
            for (int no = 0; no < 4; ++no) {
                const size_t fo = ((size_t)(kp * 8 + wcol * 4 + no) * 64 + lane) * 8;
                short8 bh = *reinterpret_cast<const short8*>(Wm + fo);
                short8 bo = *reinterpret_cast<const short8*>(Wm + 16384 + fo);
                acc[no] = __builtin_amdgcn_mfma_f32_16x16x32_bf16(aH, bh, acc[no], 0, 0, 0);
                acc[no] = __builtin_amdgcn_mfma_f32_16x16x32_bf16(aL, bh, acc[no], 0, 0, 0);
                acc[no] = __builtin_amdgcn_mfma_f32_16x16x32_bf16(aH, bo, acc[no], 0, 0, 0);
            }
        }
    }

    #pragma unroll
    for (int no = 0; no < 4; ++no) {
        const int col = wcol * 64 + no * 16 + mcol;
        const float bias = bl[col];
        #pragma unroll
        for (int ri = 0; ri < 4; ++ri) {
            const int row = rb + wrow * 16 + q * 4 + ri;
            if (row < nrows)
                xout[(size_t)row * D + col] = fmaxf(acc[no][ri] + bias, 0.f);
        }
    }
}

// ---------------- fused layer-2 + classifier ----------------
// Per 32-row block: x2 = relu(mean2[r]@W2l + b2l + x1c[map[label_pos[r]]]@W2r)
// computed via split-bf16 MFMA into LDS, then out = relu(x2@Wc1+bc1)@Wc2+bc2.
__global__ __launch_bounds__(256) void sage2_cls_k(
    const float* __restrict__ mean, const float* __restrict__ x1c,
    const int* __restrict__ label_pos, const int* __restrict__ map,
    const unsigned short* __restrict__ WlSw, const unsigned short* __restrict__ WrSw,
    const float* __restrict__ bl,
    const float* __restrict__ Wc1, const float* __restrict__ bc1,
    const float* __restrict__ Wc2, const float* __restrict__ bc2,
    float* __restrict__ out, int nrows)
{
    __shared__ float Xs[32][132];   // x2 tile (+4 pad: worst 2-way bank alias = free)
    __shared__ float Hs[32][128];
    const int rb = blockIdx.x * 32;
    const int t = threadIdx.x;
    const int wrow = (t >> 6) & 1;
    const int wcol = t >> 7;
    const int lane = t & 63;
    const int mcol = lane & 15;
    const int q = lane >> 4;
    const int r = rb + wrow * 16 + mcol;

    // ---- stage 1: MFMA (identical math to sage_mfma_k<true,true>)
    f32x4 acc[4];
    #pragma unroll
    for (int no = 0; no < 4; ++no) acc[no] = (f32x4){0.f, 0.f, 0.f, 0.f};

    size_t gidx = 0;
    if (r < nrows) gidx = (size_t)map[label_pos[r]];

    #pragma unroll
    for (int br = 0; br < 2; ++br) {
        const unsigned short* __restrict__ Wm = br ? WrSw : WlSw;
        #pragma unroll
        for (int kp = 0; kp < 4; ++kp) {
            short8 aH, aL;
            {
                float4 v0 = make_float4(0.f, 0.f, 0.f, 0.f);
                float4 v1 = make_float4(0.f, 0.f, 0.f, 0.f);
                if (r < nrows) {
                    const float* p = (br == 0)
                        ? mean + (size_t)r * D + kp * 32 + q * 8
                        : x1c + gidx * D + kp * 32 + q * 8;
                    v0 = *reinterpret_cast<const float4*>(p);
                    v1 = *reinterpret_cast<const float4*>(p + 4);
                }
                split8(v0, v1, aH, aL);
            }
            #pragma unroll
            for (int no = 0; no < 4; ++no) {
                const size_t fo = ((size_t)(kp * 8 + wcol * 4 + no) * 64 + lane) * 8;
                short8 bh = *reinterpret_cast<const short8*>(Wm + fo);
                short8 bo = *reinterpret_cast<const short8*>(Wm + 16384 + fo);
                acc[no] = __builtin_amdgcn_mfma_f32_16x16x32_bf16(aH, bh, acc[no], 0, 0, 0);
                acc[no] = __builtin_amdgcn_mfma_f32_16x16x32_bf16(aL, bh, acc[no], 0, 0, 0);
                acc[no] = __builtin_amdgcn_mfma_f32_16x16x32_bf16(aH, bo, acc[no], 0, 0, 0);
            }
        }
    }

    // epilogue -> LDS tile (unconditional: junk rows masked at final store)
    #pragma unroll
    for (int no = 0; no < 4; ++no) {
        const int col = wcol * 64 + no * 16 + mcol;
        const float bias = bl[col];
        #pragma unroll
        for (int ri = 0; ri < 4; ++ri) {
            const int lrow = wrow * 16 + q * 4 + ri;
            Xs[lrow][col] = fmaxf(acc[no][ri] + bias, 0.f);
        }
    }
    __syncthreads();

    // ---- stage 2: h = relu(x2 @ Wc1 + bc1)
    {
        const int col  = t & 127;
        const int half = t >> 7;
        float a2[16];
        const float bias = bc1[col];
        #pragma unroll
        for (int i = 0; i < 16; ++i) a2[i] = bias;
        for (int k = 0; k < 128; ++k) {
            float w = Wc1[k * 128 + col];
            #pragma unroll
            for (int i = 0; i < 16; ++i)
                a2[i] = fmaf(Xs[half * 16 + i][k], w, a2[i]);
        }
        #pragma unroll
        for (int i = 0; i < 16; ++i)
            Hs[half * 16 + i][col] = fmaxf(a2[i], 0.0f);
    }
    __syncthreads();

    // ---- stage 3: out = h @ Wc2 + bc2
    {
        const int c  = t & 31;
        const int rg = t >> 5;
        float o[4];
        const float b2 = bc2[c];
        #pragma unroll
        for (int i = 0; i < 4; ++i) o[i] = b2;
        for (int k = 0; k < 128; ++k) {
            float w = Wc2[k * 32 + c];
            #pragma unroll
            for (int i = 0; i < 4; ++i)
                o[i] = fmaf(Hs[rg + 8 * i][k], w, o[i]);
        }
        #pragma unroll
        for (int i = 0; i < 4; ++i) {
            int row = rb + rg + 8 * i;
            if (row < nrows) out[(size_t)row * C + c] = o[i];
        }
    }
}

// ---------------- launch ----------------

extern "C" void kernel_launch(void* const* d_in, const int* in_sizes, int n_in,
                              void* d_out, int out_size, void* d_ws, size_t ws_size,
                              hipStream_t stream) {
    const float* node_state = (const float*)d_in[0];
    const int*   edge_index = (const int*)d_in[1];
    const int*   label_pos  = (const int*)d_in[2];
    const float* W1l = (const float*)d_in[3];
    const float* b1l = (const float*)d_in[4];
    const float* W1r = (const float*)d_in[5];
    const float* W2l = (const float*)d_in[6];
    const float* b2l = (const float*)d_in[7];
    const float* W2r = (const float*)d_in[8];
    const float* Wc1 = (const float*)d_in[9];
    const float* bc1 = (const float*)d_in[10];
    const float* Wc2 = (const float*)d_in[11];
    const float* bc2 = (const float*)d_in[12];
    float* out = (float*)d_out;

    const int* src = edge_index;       // edge_index[0]
    const int* dst = edge_index + E;   // edge_index[1]

    // workspace layout (floats first for alignment)
    char* ws = (char*)d_ws;
    float* x1c   = (float*)ws;                    ws += sizeof(float) * (size_t)N * D;
    float* bufA  = (float*)ws;                    ws += sizeof(float) * (size_t)N * D;
    unsigned short* Wsw = (unsigned short*)ws;    ws += sizeof(unsigned short) * 4 * 32768;
    int* deg     = (int*)ws;                      ws += sizeof(int) * N;   // |
    int* flag    = (int*)ws;                      ws += sizeof(int) * N;   // | contiguous: one
    int* labflag = (int*)ws;                      ws += sizeof(int) * N;   // | memset
    int* ucnt    = (int*)ws;                      ws += sizeof(int);       // |
    float* sink  = (float*)ws;                    ws += sizeof(float);
    ws += sizeof(int) * 2;                        // pad to 16B
    int* roff    = (int*)ws;                      ws += sizeof(int) * (N + 1);
    int* cur     = (int*)ws;                      ws += sizeof(int) * N;
    int* csr_src = (int*)ws;                      ws += sizeof(int) * E;
    int* map     = (int*)ws;                      ws += sizeof(int) * N;
    int* ulist   = (int*)ws;                      ws += sizeof(int) * N;
    int* bsum    = (int*)ws;                      ws += sizeof(int) * 256;
    // bufA: mean1c [ucnt][D]; then mean2g [B][D]
    float* mean1c = bufA;
    float* mean2g = bufA;

    const int TB = 256;
    const int EB = (E + TB - 1) / TB;   // 2344 edge blocks

    // ---- preprocessing: 5 dispatches + 1 memset ----
    hipMemsetAsync(deg, 0, sizeof(int) * (3 * N + 1), stream);  // deg,flag,labflag,ucnt
    lab_k<<<(B + TB - 1) / TB, TB, 0, stream>>>(label_pos, labflag, flag, B);
    deg_swz_k<<<EB + 64 + TOUCHB, TB, 0, stream>>>(src, dst, labflag, deg, flag, E, EB,
                                                   W1l, W1r, W2l, W2r, Wsw,
                                                   node_state, sink);
    scan1m_k<<<2 * NB, 256, 0, stream>>>(deg, flag, bsum, N);   // per-array-aligned chunks
    scan3m_k<<<2 * NB, 256, 0, stream>>>(deg, flag, bsum, roff, cur, map, ulist, ucnt, N);
    fill_k<<<EB, TB, 0, stream>>>(src, dst, cur, csr_src, E);

    // ---- layer 1: only U rows (compact outputs) ----
    gather_mean_k<true, false><<<(N + 3) / 4, TB, 0, stream>>>(
        node_state, roff, csr_src, ulist, nullptr, ucnt, mean1c, N);
    sage_mfma_k<true, false><<<(N + 31) / 32, TB, 0, stream>>>(
        mean1c, node_state, ulist, nullptr, ucnt,
        Wsw, Wsw + 32768, b1l, x1c, N);

    // ---- layer 2 + classifier (fused; label rows) ----
    gather_mean_k<true, true><<<(B + 3) / 4, TB, 0, stream>>>(
        x1c, roff, csr_src, label_pos, map, nullptr, mean2g, B);
    sage2_cls_k<<<(B + 31) / 32, TB, 0, stream>>>(
        mean2g, x1c, label_pos, map,
        Wsw + 65536, Wsw + 98304, b2l,
        Wc1, bc1, Wc2, bc2, out, B);
}

// Round 21
// 258.263 us; speedup vs baseline: 1.0807x; 1.0353x over previous
//
#include <hip/hip_runtime.h>
#include <hip/hip_bf16.h>

// Problem constants (match reference setup_inputs)
static constexpr int N = 100000;
static constexpr int E = 600000;
static constexpr int D = 128;
static constexpr int B = 10000;
static constexpr int C = 32;
static constexpr int NB = (N + 1023) / 1024;   // 98 scan chunks per N-array
static constexpr int TOUCHB = (N * (D / 4) + 255) / 256;   // 12500 float4-touch blocks

typedef __attribute__((ext_vector_type(8))) short short8;   // 8 bf16 (4 VGPRs)
typedef __attribute__((ext_vector_type(4))) float f32x4;    // MFMA acc

// bf16 RNE helpers (bit-level, no NaN inputs here)
static __device__ __forceinline__ unsigned short f2bf(float f) {
    unsigned u = __float_as_uint(f);
    unsigned r = (u + 0x7FFFu + ((u >> 16) & 1u)) >> 16;
    return (unsigned short)r;
}
static __device__ __forceinline__ float bf2f(unsigned short h) {
    return __uint_as_float(((unsigned)h) << 16);
}

// split 8 consecutive floats into hi/lo bf16 fragments
static __device__ __forceinline__ void split8(const float4 v0, const float4 v1,
                                              short8& h, short8& l) {
    const float f[8] = {v0.x, v0.y, v0.z, v0.w, v1.x, v1.y, v1.z, v1.w};
    #pragma unroll
    for (int i = 0; i < 8; ++i) {
        unsigned short hh = f2bf(f[i]);
        h[i] = (short)hh;
        l[i] = (short)f2bf(f[i] - bf2f(hh));
    }
}

// ---------------- label marking ----------------
__global__ void lab_k(const int* __restrict__ label_pos, int* __restrict__ labflag,
                      int* __restrict__ flag, int nlab) {
    int i = blockIdx.x * blockDim.x + threadIdx.x;
    if (i < nlab) {
        int v = label_pos[i];
        labflag[v] = 1;
        flag[v] = 1;   // labels are in U
    }
}

// ---------------- merged edge pass (deg + U-mark) + weight swizzle + L3 touch ----------------
// blocks [0, EB): per-edge deg atomic + flag[src]=1 where dst is a label.
// blocks [EB, EB+80): swizzle fp32 W[128][128] -> MFMA-B fragment order, hi/lo bf16
//   (5 matrices: W1l, W1r, W2l, W2r, Wc1):
//   out[plane][((ko*8+no)*64+lane)*8+j] = W[ko*32+(lane>>4)*8+j][no*16+(lane&15)]
// blocks [EB+80, EB+80+TOUCHB): stream node_state into L3.
__global__ __launch_bounds__(256) void deg_swz_k(
    const int* __restrict__ src, const int* __restrict__ dst,
    const int* __restrict__ labflag,
    int* __restrict__ deg, int* __restrict__ flag, int nE, int EB,
    const float* W0, const float* W1, const float* W2, const float* W3,
    const float* W4,
    unsigned short* __restrict__ out,
    const float* __restrict__ xtouch, float* __restrict__ sink) {
    if ((int)blockIdx.x < EB) {
        int e = blockIdx.x * 256 + threadIdx.x;
        if (e < nE) {
            int d = dst[e];
            atomicAdd(&deg[d], 1);
            if (labflag[d]) flag[src[e]] = 1;   // benign race, all write 1
        }
        return;
    }
    if ((int)blockIdx.x < EB + 80) {
        const int sb = blockIdx.x - EB;          // 0..79
        const int m = sb >> 4;                   // 0..4
        const int chunk = sb & 15;
        const float* W = (m == 0) ? W0 : (m == 1) ? W1 : (m == 2) ? W2
                       : (m == 3) ? W3 : W4;
        unsigned short* o = out + (size_t)m * 32768;
        #pragma unroll
        for (int it = 0; it < 4; ++it) {
            int f = chunk * 1024 + it * 256 + threadIdx.x;   // 0..16383
            int j = f & 7;
            int lane = (f >> 3) & 63;
            int fi = f >> 9;                                 // ko*8+no
            int k = (fi >> 3) * 32 + (lane >> 4) * 8 + j;
            int n = (fi & 7) * 16 + (lane & 15);
            float a = W[k * 128 + n];
            unsigned short h = f2bf(a);
            o[f] = h;
            o[16384 + f] = f2bf(a - bf2f(h));
        }
        return;
    }
    // ---- L3 warm touch of node_state
    const int f4 = (blockIdx.x - (EB + 80)) * 256 + threadIdx.x;
    if (f4 < N * (D / 4)) {
        float4 v = reinterpret_cast<const float4*>(xtouch)[f4];
        float s = v.x + v.y + v.z + v.w;
        if (s > 1e30f) *sink = s;   // data-dependent, never taken: keeps the loads
    }
}

// merged chunk sums with PER-ARRAY-ALIGNED chunking (the r8/r16 crash was
// scanning [deg|flag] as contiguous 2N: chunk 97 straddles the boundary since
// N % 1024 != 0). blocks [0,NB) sum deg chunks; [NB,2NB) sum flag chunks.
__global__ __launch_bounds__(256) void scan1m_k(const int* __restrict__ deg,
                                                const int* __restrict__ flag,
                                                int* __restrict__ bsum, int n) {
    __shared__ int lsum[256];
    const int t = threadIdx.x;
    const bool isdeg = (int)blockIdx.x < NB;
    const int bloc = isdeg ? blockIdx.x : blockIdx.x - NB;
    const int* v = isdeg ? deg : flag;
    const int base = bloc * 1024 + t * 4;
    int s = 0;
    #pragma unroll
    for (int i = 0; i < 4; ++i) {
        int idx = base + i;
        if (idx < n) s += v[idx];
    }
    lsum[t] = s;
    __syncthreads();
    for (int off = 128; off > 0; off >>= 1) {
        if (t < off) lsum[t] += lsum[t + off];
        __syncthreads();
    }
    if (t == 0) bsum[blockIdx.x] = lsum[0];
}

// merged phase 3, fully independent groups:
// blocks [0,NB):    local scan of bsum[0..NB)   -> roff/cur from deg; block 0 writes roff[N]
// blocks [NB,2NB):  local scan of bsum[NB..2NB) -> map/ulist from flag; its block 0 writes ucnt
__global__ __launch_bounds__(256) void scan3m_k(
    const int* __restrict__ deg, const int* __restrict__ flag,
    const int* __restrict__ bsum,
    int* __restrict__ roff, int* __restrict__ cur,
    int* __restrict__ map, int* __restrict__ ulist, int* __restrict__ ucnt,
    int n)
{
    __shared__ int sb[128];
    __shared__ int lsum[256];
    const int t = threadIdx.x;
    const bool isdeg = (int)blockIdx.x < NB;
    const int bloc = isdeg ? blockIdx.x : blockIdx.x - NB;
    const int* bs = isdeg ? bsum : bsum + NB;
    const int* v  = isdeg ? deg : flag;

    // local inclusive scan of this group's NB chunk sums
    if (t < 128) sb[t] = (t < NB) ? bs[t] : 0;
    __syncthreads();
    for (int off = 1; off < 128; off <<= 1) {
        int u = (t < 128 && t >= off) ? sb[t - off] : 0;
        __syncthreads();
        if (t < 128) sb[t] += u;
        __syncthreads();
    }
    const int boff = (bloc == 0) ? 0 : sb[bloc - 1];
    if (bloc == 0 && t == 0) {
        if (isdeg) roff[n] = sb[NB - 1];   // == E
        else *ucnt = sb[NB - 1];
    }

    const int base = bloc * 1024 + t * 4;
    int d[4];
    int s = 0;
    #pragma unroll
    for (int i = 0; i < 4; ++i) {
        int idx = base + i;
        d[i] = (idx < n) ? v[idx] : 0;
        s += d[i];
    }
    lsum[t] = s;
    __syncthreads();
    for (int off = 1; off < 256; off <<= 1) {
        int u = (t >= off) ? lsum[t - off] : 0;
        __syncthreads();
        lsum[t] += u;
        __syncthreads();
    }
    int run = boff + lsum[t] - s;
    #pragma unroll
    for (int i = 0; i < 4; ++i) {
        int idx = base + i;
        if (idx < n) {
            if (isdeg) {
                roff[idx] = run;
                cur[idx]  = run;
                run += d[i];
            } else if (d[i]) {
                map[idx] = run;
                ulist[run] = idx;
                ++run;
            }
        }
    }
}

__global__ void fill_k(const int* __restrict__ src, const int* __restrict__ dst,
                       int* __restrict__ cur, int* __restrict__ csr_src, int nE) {
    int e = blockIdx.x * blockDim.x + threadIdx.x;
    if (e < nE) {
        int p = atomicAdd(&cur[dst[e]], 1);
        csr_src[p] = src[e];
    }
}

// ---------------- gather-mean aggregation (r12 v1: measured best) ----------------
template <bool GATHER, bool MAP>
__global__ __launch_bounds__(256) void gather_mean_k(
    const float* __restrict__ x, const int* __restrict__ roff,
    const int* __restrict__ csr_src, const int* __restrict__ rows,
    const int* __restrict__ map, const int* __restrict__ nrows_ptr,
    float* __restrict__ out, int nrows_max) {
    const int nrows = nrows_ptr ? nrows_ptr[0] : nrows_max;
    const int w = blockIdx.x * (blockDim.x >> 6) + (threadIdx.x >> 6);
    if (w >= nrows) return;
    const int lane = threadIdx.x & 63;
    const int n  = GATHER ? rows[w] : w;
    const int jb = roff[n];
    const int je = roff[n + 1];
    const float* xb = x + lane * 2;

    float ax = 0.f, ay = 0.f;
    int j = jb;
    for (; j + 4 <= je; j += 4) {
        int s0 = csr_src[j + 0];
        int s1 = csr_src[j + 1];
        int s2 = csr_src[j + 2];
        int s3 = csr_src[j + 3];
        if (MAP) { s0 = map[s0]; s1 = map[s1]; s2 = map[s2]; s3 = map[s3]; }
        float2 v0 = *reinterpret_cast<const float2*>(xb + (size_t)s0 * D);
        float2 v1 = *reinterpret_cast<const float2*>(xb + (size_t)s1 * D);
        float2 v2 = *reinterpret_cast<const float2*>(xb + (size_t)s2 * D);
        float2 v3 = *reinterpret_cast<const float2*>(xb + (size_t)s3 * D);
        ax += v0.x + v1.x + v2.x + v3.x;
        ay += v0.y + v1.y + v2.y + v3.y;
    }
    for (; j < je; ++j) {
        int s = csr_src[j];
        if (MAP) s = map[s];
        float2 v = *reinterpret_cast<const float2*>(xb + (size_t)s * D);
        ax += v.x;
        ay += v.y;
    }
    const float inv = 1.0f / fmaxf((float)(je - jb), 1.0f);
    *reinterpret_cast<float2*>(out + (size_t)w * D + lane * 2) =
        make_float2(ax * inv, ay * inv);
}

// ---------------- SAGE layer 1, split-bf16 MFMA, LDS-free / barrier-free ----------------
// 32-row blocks, 4 waves = {row-half} x {col-half}; each wave 16 rows x 64 cols.
template <bool GATHER, bool MAP>
__global__ __launch_bounds__(256, 6) void sage_mfma_k(
    const float* __restrict__ mean, const float* __restrict__ xsrc,
    const int* __restrict__ rows, const int* __restrict__ map,
    const int* __restrict__ nrows_ptr,
    const unsigned short* __restrict__ WlSw, const unsigned short* __restrict__ WrSw,
    const float* __restrict__ bl, float* __restrict__ xout, int nrows_max)
{
    const int nrows = nrows_ptr ? nrows_ptr[0] : nrows_max;
    const int rb = blockIdx.x * 32;
    if (rb >= nrows) return;

    const int t = threadIdx.x;
    const int wrow = (t >> 6) & 1;
    const int wcol = t >> 7;
    const int lane = t & 63;
    const int mcol = lane & 15;
    const int q = lane >> 4;
    const int r = rb + wrow * 16 + mcol;

    f32x4 acc[4];
    #pragma unroll
    for (int no = 0; no < 4; ++no) acc[no] = (f32x4){0.f, 0.f, 0.f, 0.f};

    size_t gidx = 0;
    if (r < nrows) {
        int g = GATHER ? rows[r] : r;
        if (MAP) g = map[g];
        gidx = (size_t)g;
    }

    #pragma unroll
    for (int br = 0; br < 2; ++br) {
        const unsigned short* __restrict__ Wm = br ? WrSw : WlSw;
        #pragma unroll
        for (int kp = 0; kp < 4; ++kp) {
            short8 aH, aL;
            {
                float4 v0 = make_float4(0.f, 0.f, 0.f, 0.f);
                float4 v1 = make_float4(0.f, 0.f, 0.f, 0.f);
                if (r < nrows) {
                    const float* p = (br == 0)
                        ? mean + (size_t)r * D + kp * 32 + q * 8
                        : xsrc + gidx * D + kp * 32 + q * 8;
                    v0 = *reinterpret_cast<const float4*>(p);
                    v1 = *reinterpret_cast<const float4*>(p + 4);
                }
                split8(v0, v1, aH, aL);
            }
            #pragma unroll
            for (int no = 0; no < 4; ++no) {
                const size_t fo = ((size_t)(kp * 8 + wcol * 4 + no) * 64 + lane) * 8;
                short8 bh = *reinterpret_cast<const short8*>(Wm + fo);
                short8 bo = *reinterpret_cast<const short8*>(Wm + 16384 + fo);
                acc[no] = __builtin_amdgcn_mfma_f32_16x16x32_bf16(aH, bh, acc[no], 0, 0, 0);
                acc[no] = __builtin_amdgcn_mfma_f32_16x16x32_bf16(aL, bh, acc[no], 0, 0, 0);
                acc[no] = __builtin_amdgcn_mfma_f32_16x16x32_bf16(aH, bo, acc[no], 0, 0, 0);
            }
        }
    }

    #pragma unroll
    for (int no = 0; no < 4; ++no) {
        const int col = wcol * 64 + no * 16 + mcol;
        const float bias = bl[col];
        #pragma unroll
        for (int ri = 0; ri < 4; ++ri) {
            const int row = rb + wrow * 16 + q * 4 + ri;
            if (row < nrows)
                xout[(size_t)row * D + col] = fmaxf(acc[no][ri] + bias, 0.f);
        }
    }
}

// ---------------- fused layer-2 + classifier (classifier stage 2 now MFMA) ----------------
// Per 32-row block:
//   stage 1: x2 = relu(mean2[r]@W2l + b2l + x1c[map[label_pos[r]]]@W2r)  (MFMA -> Xs LDS)
//   stage 2: h = relu(x2 @ Wc1 + bc1)   (split-bf16 MFMA, A-frags from Xs -> Hs LDS)
//   stage 3: out = h @ Wc2 + bc2        (scalar, small: C=32)
__global__ __launch_bounds__(256) void sage2_cls_k(
    const float* __restrict__ mean, const float* __restrict__ x1c,
    const int* __restrict__ label_pos, const int* __restrict__ map,
    const unsigned short* __restrict__ WlSw, const unsigned short* __restrict__ WrSw,
    const float* __restrict__ bl,
    const unsigned short* __restrict__ Wc1Sw, const float* __restrict__ bc1,
    const float* __restrict__ Wc2, const float* __restrict__ bc2,
    float* __restrict__ out, int nrows)
{
    __shared__ alignas(16) float Xs[32][132];   // x2 tile (+4 pad)
    __shared__ float Hs[32][128];
    const int rb = blockIdx.x * 32;
    const int t = threadIdx.x;
    const int wrow = (t >> 6) & 1;
    const int wcol = t >> 7;
    const int lane = t & 63;
    const int mcol = lane & 15;
    const int q = lane >> 4;
    const int r = rb + wrow * 16 + mcol;

    // ---- stage 1: MFMA (identical math to sage_mfma_k<true,true>)
    f32x4 acc[4];
    #pragma unroll
    for (int no = 0; no < 4; ++no) acc[no] = (f32x4){0.f, 0.f, 0.f, 0.f};

    size_t gidx = 0;
    if (r < nrows) gidx = (size_t)map[label_pos[r]];

    #pragma unroll
    for (int br = 0; br < 2; ++br) {
        const unsigned short* __restrict__ Wm = br ? WrSw : WlSw;
        #pragma unroll
        for (int kp = 0; kp < 4; ++kp) {
            short8 aH, aL;
            {
                float4 v0 = make_float4(0.f, 0.f, 0.f, 0.f);
                float4 v1 = make_float4(0.f, 0.f, 0.f, 0.f);
                if (r < nrows) {
                    const float* p = (br == 0)
                        ? mean + (size_t)r * D + kp * 32 + q * 8
                        : x1c + gidx * D + kp * 32 + q * 8;
                    v0 = *reinterpret_cast<const float4*>(p);
                    v1 = *reinterpret_cast<const float4*>(p + 4);
                }
                split8(v0, v1, aH, aL);
            }
            #pragma unroll
            for (int no = 0; no < 4; ++no) {
                const size_t fo = ((size_t)(kp * 8 + wcol * 4 + no) * 64 + lane) * 8;
                short8 bh = *reinterpret_cast<const short8*>(Wm + fo);
                short8 bo = *reinterpret_cast<const short8*>(Wm + 16384 + fo);
                acc[no] = __builtin_amdgcn_mfma_f32_16x16x32_bf16(aH, bh, acc[no], 0, 0, 0);
                acc[no] = __builtin_amdgcn_mfma_f32_16x16x32_bf16(aL, bh, acc[no], 0, 0, 0);
                acc[no] = __builtin_amdgcn_mfma_f32_16x16x32_bf16(aH, bo, acc[no], 0, 0, 0);
            }
        }
    }

    // epilogue -> LDS tile (unconditional: junk rows masked at final store)
    #pragma unroll
    for (int no = 0; no < 4; ++no) {
        const int col = wcol * 64 + no * 16 + mcol;
        const float bias = bl[col];
        #pragma unroll
        for (int ri = 0; ri < 4; ++ri) {
            const int lrow = wrow * 16 + q * 4 + ri;
            Xs[lrow][col] = fmaxf(acc[no][ri] + bias, 0.f);
        }
    }
    __syncthreads();

    // ---- stage 2: h = relu(x2 @ Wc1 + bc1), split-bf16 MFMA, A from Xs
    {
        f32x4 acc2[4];
        #pragma unroll
        for (int no = 0; no < 4; ++no) acc2[no] = (f32x4){0.f, 0.f, 0.f, 0.f};

        #pragma unroll
        for (int kp = 0; kp < 4; ++kp) {
            short8 aH, aL;
            {
                const float* p = &Xs[wrow * 16 + mcol][kp * 32 + q * 8];
                float4 v0 = *reinterpret_cast<const float4*>(p);
                float4 v1 = *reinterpret_cast<const float4*>(p + 4);
                split8(v0, v1, aH, aL);
            }
            #pragma unroll
            for (int no = 0; no < 4; ++no) {
                const size_t fo = ((size_t)(kp * 8 + wcol * 4 + no) * 64 + lane) * 8;
                short8 bh = *reinterpret_cast<const short8*>(Wc1Sw + fo);
                short8 bo = *reinterpret_cast<const short8*>(Wc1Sw + 16384 + fo);
                acc2[no] = __builtin_amdgcn_mfma_f32_16x16x32_bf16(aH, bh, acc2[no], 0, 0, 0);
                acc2[no] = __builtin_amdgcn_mfma_f32_16x16x32_bf16(aL, bh, acc2[no], 0, 0, 0);
                acc2[no] = __builtin_amdgcn_mfma_f32_16x16x32_bf16(aH, bo, acc2[no], 0, 0, 0);
            }
        }
        __syncthreads();   // ensure all waves done reading Xs before Hs writes race anything
        #pragma unroll
        for (int no = 0; no < 4; ++no) {
            const int col = wcol * 64 + no * 16 + mcol;
            const float bias = bc1[col];
            #pragma unroll
            for (int ri = 0; ri < 4; ++ri) {
                const int lrow = wrow * 16 + q * 4 + ri;
                Hs[lrow][col] = fmaxf(acc2[no][ri] + bias, 0.0f);
            }
        }
    }
    __syncthreads();

    // ---- stage 3: out = h @ Wc2 + bc2 (scalar; small)
    {
        const int c  = t & 31;
        const int rg = t >> 5;
        float o[4];
        const float b2 = bc2[c];
        #pragma unroll
        for (int i = 0; i < 4; ++i) o[i] = b2;
        for (int k = 0; k < 128; ++k) {
            float w = Wc2[k * 32 + c];
            #pragma unroll
            for (int i = 0; i < 4; ++i)
                o[i] = fmaf(Hs[rg + 8 * i][k], w, o[i]);
        }
        #pragma unroll
        for (int i = 0; i < 4; ++i) {
            int row = rb + rg + 8 * i;
            if (row < nrows) out[(size_t)row * C + c] = o[i];
        }
    }
}

// ---------------- launch ----------------

extern "C" void kernel_launch(void* const* d_in, const int* in_sizes, int n_in,
                              void* d_out, int out_size, void* d_ws, size_t ws_size,
                              hipStream_t stream) {
    const float* node_state = (const float*)d_in[0];
    const int*   edge_index = (const int*)d_in[1];
    const int*   label_pos  = (const int*)d_in[2];
    const float* W1l = (const float*)d_in[3];
    const float* b1l = (const float*)d_in[4];
    const float* W1r = (const float*)d_in[5];
    const float* W2l = (const float*)d_in[6];
    const float* b2l = (const float*)d_in[7];
    const float* W2r = (const float*)d_in[8];
    const float* Wc1 = (const float*)d_in[9];
    const float* bc1 = (const float*)d_in[10];
    const float* Wc2 = (const float*)d_in[11];
    const float* bc2 = (const float*)d_in[12];
    float* out = (float*)d_out;

    const int* src = edge_index;       // edge_index[0]
    const int* dst = edge_index + E;   // edge_index[1]

    // workspace layout (floats first for alignment)
    char* ws = (char*)d_ws;
    float* x1c   = (float*)ws;                    ws += sizeof(float) * (size_t)N * D;
    float* bufA  = (float*)ws;                    ws += sizeof(float) * (size_t)N * D;
    unsigned short* Wsw = (unsigned short*)ws;    ws += sizeof(unsigned short) * 5 * 32768;
    int* deg     = (int*)ws;                      ws += sizeof(int) * N;   // |
    int* flag    = (int*)ws;                      ws += sizeof(int) * N;   // | contiguous: one
    int* labflag = (int*)ws;                      ws += sizeof(int) * N;   // | memset
    int* ucnt    = (int*)ws;                      ws += sizeof(int);       // |
    float* sink  = (float*)ws;                    ws += sizeof(float);
    ws += sizeof(int) * 2;                        // pad to 16B
    int* roff    = (int*)ws;                      ws += sizeof(int) * (N + 1);
    int* cur     = (int*)ws;                      ws += sizeof(int) * N;
    int* csr_src = (int*)ws;                      ws += sizeof(int) * E;
    int* map     = (int*)ws;                      ws += sizeof(int) * N;
    int* ulist   = (int*)ws;                      ws += sizeof(int) * N;
    int* bsum    = (int*)ws;                      ws += sizeof(int) * 256;
    // bufA: mean1c [ucnt][D]; then mean2g [B][D]
    float* mean1c = bufA;
    float* mean2g = bufA;

    const int TB = 256;
    const int EB = (E + TB - 1) / TB;   // 2344 edge blocks

    // ---- preprocessing: 5 dispatches + 1 memset ----
    hipMemsetAsync(deg, 0, sizeof(int) * (3 * N + 1), stream);  // deg,flag,labflag,ucnt
    lab_k<<<(B + TB - 1) / TB, TB, 0, stream>>>(label_pos, labflag, flag, B);
    deg_swz_k<<<EB + 80 + TOUCHB, TB, 0, stream>>>(src, dst, labflag, deg, flag, E, EB,
                                                   W1l, W1r, W2l, W2r, Wc1, Wsw,
                                                   node_state, sink);
    scan1m_k<<<2 * NB, 256, 0, stream>>>(deg, flag, bsum, N);   // per-array-aligned chunks
    scan3m_k<<<2 * NB, 256, 0, stream>>>(deg, flag, bsum, roff, cur, map, ulist, ucnt, N);
    fill_k<<<EB, TB, 0, stream>>>(src, dst, cur, csr_src, E);

    // ---- layer 1: only U rows (compact outputs) ----
    gather_mean_k<true, false><<<(N + 3) / 4, TB, 0, stream>>>(
        node_state, roff, csr_src, ulist, nullptr, ucnt, mean1c, N);
    sage_mfma_k<true, false><<<(N + 31) / 32, TB, 0, stream>>>(
        mean1c, node_state, ulist, nullptr, ucnt,
        Wsw, Wsw + 32768, b1l, x1c, N);

    // ---- layer 2 + classifier (fused; label rows; stage-2 MFMA) ----
    gather_mean_k<true, true><<<(B + 3) / 4, TB, 0, stream>>>(
        x1c, roff, csr_src, label_pos, map, nullptr, mean2g, B);
    sage2_cls_k<<<(B + 31) / 32, TB, 0, stream>>>(
        mean2g, x1c, label_pos, map,
        Wsw + 65536, Wsw + 98304, b2l,
        Wsw + 131072, bc1, Wc2, bc2, out, B);
}

// Round 22
// 252.821 us; speedup vs baseline: 1.1040x; 1.0215x over previous
//
#include <hip/hip_runtime.h>
#include <hip/hip_bf16.h>

// Problem constants (match reference setup_inputs)
static constexpr int N = 100000;
static constexpr int E = 600000;
static constexpr int D = 128;
static constexpr int B = 10000;
static constexpr int C = 32;
static constexpr int NB = (N + 1023) / 1024;   // 98 scan chunks per N-array
static constexpr int TOUCHB = (N * (D / 4) + 255) / 256;   // 12500 float4-touch blocks

typedef __attribute__((ext_vector_type(8))) short short8;   // 8 bf16 (4 VGPRs)
typedef __attribute__((ext_vector_type(4))) float f32x4;    // MFMA acc

// bf16 RNE helpers (bit-level, no NaN inputs here)
static __device__ __forceinline__ unsigned short f2bf(float f) {
    unsigned u = __float_as_uint(f);
    unsigned r = (u + 0x7FFFu + ((u >> 16) & 1u)) >> 16;
    return (unsigned short)r;
}
static __device__ __forceinline__ float bf2f(unsigned short h) {
    return __uint_as_float(((unsigned)h) << 16);
}

// split 8 consecutive floats into hi/lo bf16 fragments
static __device__ __forceinline__ void split8(const float4 v0, const float4 v1,
                                              short8& h, short8& l) {
    const float f[8] = {v0.x, v0.y, v0.z, v0.w, v1.x, v1.y, v1.z, v1.w};
    #pragma unroll
    for (int i = 0; i < 8; ++i) {
        unsigned short hh = f2bf(f[i]);
        h[i] = (short)hh;
        l[i] = (short)f2bf(f[i] - bf2f(hh));
    }
}

// ---------------- label marking ----------------
__global__ void lab_k(const int* __restrict__ label_pos, int* __restrict__ labflag,
                      int* __restrict__ flag, int nlab) {
    int i = blockIdx.x * blockDim.x + threadIdx.x;
    if (i < nlab) {
        int v = label_pos[i];
        labflag[v] = 1;
        flag[v] = 1;   // labels are in U
    }
}

// ---------------- merged edge pass (deg + U-mark) + weight swizzle + L3 touch ----------------
// blocks [0, EB): per-edge deg atomic + flag[src]=1 where dst is a label.
// blocks [EB, EB+80): swizzle fp32 W[128][128] -> MFMA-B fragment order, hi/lo bf16
//   (5 matrices: W1l, W1r, W2l, W2r, Wc1):
//   out[plane][((ko*8+no)*64+lane)*8+j] = W[ko*32+(lane>>4)*8+j][no*16+(lane&15)]
// block  EB+80: swizzle Wc2 (128x32), fragment order with 2 col tiles:
//   o2[plane][((kp*2+no2)*64+lane)*8+j] = Wc2[kp*32+(lane>>4)*8+j][no2*16+(lane&15)]
// blocks [EB+81, EB+81+TOUCHB): stream node_state into L3.
__global__ __launch_bounds__(256) void deg_swz_k(
    const int* __restrict__ src, const int* __restrict__ dst,
    const int* __restrict__ labflag,
    int* __restrict__ deg, int* __restrict__ flag, int nE, int EB,
    const float* W0, const float* W1, const float* W2, const float* W3,
    const float* W4, const float* W5,
    unsigned short* __restrict__ out,
    const float* __restrict__ xtouch, float* __restrict__ sink) {
    if ((int)blockIdx.x < EB) {
        int e = blockIdx.x * 256 + threadIdx.x;
        if (e < nE) {
            int d = dst[e];
            atomicAdd(&deg[d], 1);
            if (labflag[d]) flag[src[e]] = 1;   // benign race, all write 1
        }
        return;
    }
    if ((int)blockIdx.x < EB + 80) {
        const int sb = blockIdx.x - EB;          // 0..79
        const int m = sb >> 4;                   // 0..4
        const int chunk = sb & 15;
        const float* W = (m == 0) ? W0 : (m == 1) ? W1 : (m == 2) ? W2
                       : (m == 3) ? W3 : W4;
        unsigned short* o = out + (size_t)m * 32768;
        #pragma unroll
        for (int it = 0; it < 4; ++it) {
            int f = chunk * 1024 + it * 256 + threadIdx.x;   // 0..16383
            int j = f & 7;
            int lane = (f >> 3) & 63;
            int fi = f >> 9;                                 // ko*8+no
            int k = (fi >> 3) * 32 + (lane >> 4) * 8 + j;
            int n = (fi & 7) * 16 + (lane & 15);
            float a = W[k * 128 + n];
            unsigned short h = f2bf(a);
            o[f] = h;
            o[16384 + f] = f2bf(a - bf2f(h));
        }
        return;
    }
    if ((int)blockIdx.x == EB + 80) {
        // Wc2 swizzle: 128x32 -> 8 fragments per plane (4 k-chunks x 2 col tiles)
        unsigned short* o2 = out + (size_t)5 * 32768;
        #pragma unroll
        for (int it = 0; it < 16; ++it) {
            int f = it * 256 + threadIdx.x;   // 0..4095
            int j = f & 7;
            int lane = (f >> 3) & 63;
            int fi = f >> 9;                  // 0..7 = kp*2+no2
            int k = (fi >> 1) * 32 + (lane >> 4) * 8 + j;
            int n = (fi & 1) * 16 + (lane & 15);
            float a = W5[k * 32 + n];
            unsigned short h = f2bf(a);
            o2[f] = h;
            o2[4096 + f] = f2bf(a - bf2f(h));
        }
        return;
    }
    // ---- L3 warm touch of node_state
    const int f4 = (blockIdx.x - (EB + 81)) * 256 + threadIdx.x;
    if (f4 < N * (D / 4)) {
        float4 v = reinterpret_cast<const float4*>(xtouch)[f4];
        float s = v.x + v.y + v.z + v.w;
        if (s > 1e30f) *sink = s;   // data-dependent, never taken: keeps the loads
    }
}

// merged chunk sums with PER-ARRAY-ALIGNED chunking (the r8/r16 crash was
// scanning [deg|flag] as contiguous 2N: chunk 97 straddles the boundary since
// N % 1024 != 0). blocks [0,NB) sum deg chunks; [NB,2NB) sum flag chunks.
__global__ __launch_bounds__(256) void scan1m_k(const int* __restrict__ deg,
                                                const int* __restrict__ flag,
                                                int* __restrict__ bsum, int n) {
    __shared__ int lsum[256];
    const int t = threadIdx.x;
    const bool isdeg = (int)blockIdx.x < NB;
    const int bloc = isdeg ? blockIdx.x : blockIdx.x - NB;
    const int* v = isdeg ? deg : flag;
    const int base = bloc * 1024 + t * 4;
    int s = 0;
    #pragma unroll
    for (int i = 0; i < 4; ++i) {
        int idx = base + i;
        if (idx < n) s += v[idx];
    }
    lsum[t] = s;
    __syncthreads();
    for (int off = 128; off > 0; off >>= 1) {
        if (t < off) lsum[t] += lsum[t + off];
        __syncthreads();
    }
    if (t == 0) bsum[blockIdx.x] = lsum[0];
}

// merged phase 3, fully independent groups:
// blocks [0,NB):    local scan of bsum[0..NB)   -> roff/cur from deg; block 0 writes roff[N]
// blocks [NB,2NB):  local scan of bsum[NB..2NB) -> map/ulist from flag; its block 0 writes ucnt
__global__ __launch_bounds__(256) void scan3m_k(
    const int* __restrict__ deg, const int* __restrict__ flag,
    const int* __restrict__ bsum,
    int* __restrict__ roff, int* __restrict__ cur,
    int* __restrict__ map, int* __restrict__ ulist, int* __restrict__ ucnt,
    int n)
{
    __shared__ int sb[128];
    __shared__ int lsum[256];
    const int t = threadIdx.x;
    const bool isdeg = (int)blockIdx.x < NB;
    const int bloc = isdeg ? blockIdx.x : blockIdx.x - NB;
    const int* bs = isdeg ? bsum : bsum + NB;
    const int* v  = isdeg ? deg : flag;

    // local inclusive scan of this group's NB chunk sums
    if (t < 128) sb[t] = (t < NB) ? bs[t] : 0;
    __syncthreads();
    for (int off = 1; off < 128; off <<= 1) {
        int u = (t < 128 && t >= off) ? sb[t - off] : 0;
        __syncthreads();
        if (t < 128) sb[t] += u;
        __syncthreads();
    }
    const int boff = (bloc == 0) ? 0 : sb[bloc - 1];
    if (bloc == 0 && t == 0) {
        if (isdeg) roff[n] = sb[NB - 1];   // == E
        else *ucnt = sb[NB - 1];
    }

    const int base = bloc * 1024 + t * 4;
    int d[4];
    int s = 0;
    #pragma unroll
    for (int i = 0; i < 4; ++i) {
        int idx = base + i;
        d[i] = (idx < n) ? v[idx] : 0;
        s += d[i];
    }
    lsum[t] = s;
    __syncthreads();
    for (int off = 1; off < 256; off <<= 1) {
        int u = (t >= off) ? lsum[t - off] : 0;
        __syncthreads();
        lsum[t] += u;
        __syncthreads();
    }
    int run = boff + lsum[t] - s;
    #pragma unroll
    for (int i = 0; i < 4; ++i) {
        int idx = base + i;
        if (idx < n) {
            if (isdeg) {
                roff[idx] = run;
                cur[idx]  = run;
                run += d[i];
            } else if (d[i]) {
                map[idx] = run;
                ulist[run] = idx;
                ++run;
            }
        }
    }
}

__global__ void fill_k(const int* __restrict__ src, const int* __restrict__ dst,
                       int* __restrict__ cur, int* __restrict__ csr_src, int nE) {
    int e = blockIdx.x * blockDim.x + threadIdx.x;
    if (e < nE) {
        int p = atomicAdd(&cur[dst[e]], 1);
        csr_src[p] = src[e];
    }
}

// ---------------- gather-mean aggregation (r12 v1: measured best) ----------------
template <bool GATHER, bool MAP>
__global__ __launch_bounds__(256) void gather_mean_k(
    const float* __restrict__ x, const int* __restrict__ roff,
    const int* __restrict__ csr_src, const int* __restrict__ rows,
    const int* __restrict__ map, const int* __restrict__ nrows_ptr,
    float* __restrict__ out, int nrows_max) {
    const int nrows = nrows_ptr ? nrows_ptr[0] : nrows_max;
    const int w = blockIdx.x * (blockDim.x >> 6) + (threadIdx.x >> 6);
    if (w >= nrows) return;
    const int lane = threadIdx.x & 63;
    const int n  = GATHER ? rows[w] : w;
    const int jb = roff[n];
    const int je = roff[n + 1];
    const float* xb = x + lane * 2;

    float ax = 0.f, ay = 0.f;
    int j = jb;
    for (; j + 4 <= je; j += 4) {
        int s0 = csr_src[j + 0];
        int s1 = csr_src[j + 1];
        int s2 = csr_src[j + 2];
        int s3 = csr_src[j + 3];
        if (MAP) { s0 = map[s0]; s1 = map[s1]; s2 = map[s2]; s3 = map[s3]; }
        float2 v0 = *reinterpret_cast<const float2*>(xb + (size_t)s0 * D);
        float2 v1 = *reinterpret_cast<const float2*>(xb + (size_t)s1 * D);
        float2 v2 = *reinterpret_cast<const float2*>(xb + (size_t)s2 * D);
        float2 v3 = *reinterpret_cast<const float2*>(xb + (size_t)s3 * D);
        ax += v0.x + v1.x + v2.x + v3.x;
        ay += v0.y + v1.y + v2.y + v3.y;
    }
    for (; j < je; ++j) {
        int s = csr_src[j];
        if (MAP) s = map[s];
        float2 v = *reinterpret_cast<const float2*>(xb + (size_t)s * D);
        ax += v.x;
        ay += v.y;
    }
    const float inv = 1.0f / fmaxf((float)(je - jb), 1.0f);
    *reinterpret_cast<float2*>(out + (size_t)w * D + lane * 2) =
        make_float2(ax * inv, ay * inv);
}

// ---------------- SAGE layer 1, split-bf16 MFMA, LDS-free / barrier-free ----------------
// 32-row blocks, 4 waves = {row-half} x {col-half}; each wave 16 rows x 64 cols.
template <bool GATHER, bool MAP>
__global__ __launch_bounds__(256, 6) void sage_mfma_k(
    const float* __restrict__ mean, const float* __restrict__ xsrc,
    const int* __restrict__ rows, const int* __restrict__ map,
    const int* __restrict__ nrows_ptr,
    const unsigned short* __restrict__ WlSw, const unsigned short* __restrict__ WrSw,
    const float* __restrict__ bl, float* __restrict__ xout, int nrows_max)
{
    const int nrows = nrows_ptr ? nrows_ptr[0] : nrows_max;
    const int rb = blockIdx.x * 32;
    if (rb >= nrows) return;

    const int t = threadIdx.x;
    const int wrow = (t >> 6) & 1;
    const int wcol = t >> 7;
    const int lane = t & 63;
    const int mcol = lane & 15;
    const int q = lane >> 4;
    const int r = rb + wrow * 16 + mcol;

    f32x4 acc[4];
    #pragma unroll
    for (int no = 0; no < 4; ++no) acc[no] = (f32x4){0.f, 0.f, 0.f, 0.f};

    size_t gidx = 0;
    if (r < nrows) {
        int g = GATHER ? rows[r] : r;
        if (MAP) g = map[g];
        gidx = (size_t)g;
    }

    #pragma unroll
    for (int br = 0; br < 2; ++br) {
        const unsigned short* __restrict__ Wm = br ? WrSw : WlSw;
        #pragma unroll
        for (int kp = 0; kp < 4; ++kp) {
            short8 aH, aL;
            {
                float4 v0 = make_float4(0.f, 0.f, 0.f, 0.f);
                float4 v1 = make_float4(0.f, 0.f, 0.f, 0.f);
                if (r < nrows) {
                    const float* p = (br == 0)
                        ? mean + (size_t)r * D + kp * 32 + q * 8
                        : xsrc + gidx * D + kp * 32 + q * 8;
                    v0 = *reinterpret_cast<const float4*>(p);
                    v1 = *reinterpret_cast<const float4*>(p + 4);
                }
                split8(v0, v1, aH, aL);
            }
            #pragma unroll
            for (int no = 0; no < 4; ++no) {
                const size_t fo = ((size_t)(kp * 8 + wcol * 4 + no) * 64 + lane) * 8;
                short8 bh = *reinterpret_cast<const short8*>(Wm + fo);
                short8 bo = *reinterpret_cast<const short8*>(Wm + 16384 + fo);
                acc[no] = __builtin_amdgcn_mfma_f32_16x16x32_bf16(aH, bh, acc[no], 0, 0, 0);
                acc[no] = __builtin_amdgcn_mfma_f32_16x16x32_bf16(aL, bh, acc[no], 0, 0, 0);
                acc[no] = __builtin_amdgcn_mfma_f32_16x16x32_bf16(aH, bo, acc[no], 0, 0, 0);
            }
        }
    }

    #pragma unroll
    for (int no = 0; no < 4; ++no) {
        const int col = wcol * 64 + no * 16 + mcol;
        const float bias = bl[col];
        #pragma unroll
        for (int ri = 0; ri < 4; ++ri) {
            const int row = rb + wrow * 16 + q * 4 + ri;
            if (row < nrows)
                xout[(size_t)row * D + col] = fmaxf(acc[no][ri] + bias, 0.f);
        }
    }
}

// ---------------- fused layer-2 + classifier (all three stages MFMA-capable) ----------------
// Per 32-row block:
//   stage 1: x2 = relu(mean2[r]@W2l + b2l + x1c[map[label_pos[r]]]@W2r)  (MFMA -> Xs LDS)
//   stage 2: h = relu(x2 @ Wc1 + bc1)   (split-bf16 MFMA, A-frags from Xs -> Hs LDS)
//   stage 3: out = h @ Wc2 + bc2        (split-bf16 MFMA, 16x16 tile per wave)
__global__ __launch_bounds__(256) void sage2_cls_k(
    const float* __restrict__ mean, const float* __restrict__ x1c,
    const int* __restrict__ label_pos, const int* __restrict__ map,
    const unsigned short* __restrict__ WlSw, const unsigned short* __restrict__ WrSw,
    const float* __restrict__ bl,
    const unsigned short* __restrict__ Wc1Sw, const float* __restrict__ bc1,
    const unsigned short* __restrict__ Wc2Sw, const float* __restrict__ bc2,
    float* __restrict__ out, int nrows)
{
    __shared__ alignas(16) float Xs[32][132];   // x2 tile (+4 pad)
    __shared__ alignas(16) float Hs[32][132];   // h tile (+4 pad: conflict-free A-reads)
    const int rb = blockIdx.x * 32;
    const int t = threadIdx.x;
    const int wrow = (t >> 6) & 1;
    const int wcol = t >> 7;
    const int lane = t & 63;
    const int mcol = lane & 15;
    const int q = lane >> 4;
    const int r = rb + wrow * 16 + mcol;

    // ---- stage 1: MFMA (identical math to sage_mfma_k<true,true>)
    f32x4 acc[4];
    #pragma unroll
    for (int no = 0; no < 4; ++no) acc[no] = (f32x4){0.f, 0.f, 0.f, 0.f};

    size_t gidx = 0;
    if (r < nrows) gidx = (size_t)map[label_pos[r]];

    #pragma unroll
    for (int br = 0; br < 2; ++br) {
        const unsigned short* __restrict__ Wm = br ? WrSw : WlSw;
        #pragma unroll
        for (int kp = 0; kp < 4; ++kp) {
            short8 aH, aL;
            {
                float4 v0 = make_float4(0.f, 0.f, 0.f, 0.f);
                float4 v1 = make_float4(0.f, 0.f, 0.f, 0.f);
                if (r < nrows) {
                    const float* p = (br == 0)
                        ? mean + (size_t)r * D + kp * 32 + q * 8
                        : x1c + gidx * D + kp * 32 + q * 8;
                    v0 = *reinterpret_cast<const float4*>(p);
                    v1 = *reinterpret_cast<const float4*>(p + 4);
                }
                split8(v0, v1, aH, aL);
            }
            #pragma unroll
            for (int no = 0; no < 4; ++no) {
                const size_t fo = ((size_t)(kp * 8 + wcol * 4 + no) * 64 + lane) * 8;
                short8 bh = *reinterpret_cast<const short8*>(Wm + fo);
                short8 bo = *reinterpret_cast<const short8*>(Wm + 16384 + fo);
                acc[no] = __builtin_amdgcn_mfma_f32_16x16x32_bf16(aH, bh, acc[no], 0, 0, 0);
                acc[no] = __builtin_amdgcn_mfma_f32_16x16x32_bf16(aL, bh, acc[no], 0, 0, 0);
                acc[no] = __builtin_amdgcn_mfma_f32_16x16x32_bf16(aH, bo, acc[no], 0, 0, 0);
            }
        }
    }

    // epilogue -> LDS tile (unconditional: junk rows masked at final store)
    #pragma unroll
    for (int no = 0; no < 4; ++no) {
        const int col = wcol * 64 + no * 16 + mcol;
        const float bias = bl[col];
        #pragma unroll
        for (int ri = 0; ri < 4; ++ri) {
            const int lrow = wrow * 16 + q * 4 + ri;
            Xs[lrow][col] = fmaxf(acc[no][ri] + bias, 0.f);
        }
    }
    __syncthreads();

    // ---- stage 2: h = relu(x2 @ Wc1 + bc1), split-bf16 MFMA, A from Xs
    {
        f32x4 acc2[4];
        #pragma unroll
        for (int no = 0; no < 4; ++no) acc2[no] = (f32x4){0.f, 0.f, 0.f, 0.f};

        #pragma unroll
        for (int kp = 0; kp < 4; ++kp) {
            short8 aH, aL;
            {
                const float* p = &Xs[wrow * 16 + mcol][kp * 32 + q * 8];
                float4 v0 = *reinterpret_cast<const float4*>(p);
                float4 v1 = *reinterpret_cast<const float4*>(p + 4);
                split8(v0, v1, aH, aL);
            }
            #pragma unroll
            for (int no = 0; no < 4; ++no) {
                const size_t fo = ((size_t)(kp * 8 + wcol * 4 + no) * 64 + lane) * 8;
                short8 bh = *reinterpret_cast<const short8*>(Wc1Sw + fo);
                short8 bo = *reinterpret_cast<const short8*>(Wc1Sw + 16384 + fo);
                acc2[no] = __builtin_amdgcn_mfma_f32_16x16x32_bf16(aH, bh, acc2[no], 0, 0, 0);
                acc2[no] = __builtin_amdgcn_mfma_f32_16x16x32_bf16(aL, bh, acc2[no], 0, 0, 0);
                acc2[no] = __builtin_amdgcn_mfma_f32_16x16x32_bf16(aH, bo, acc2[no], 0, 0, 0);
            }
        }
        #pragma unroll
        for (int no = 0; no < 4; ++no) {
            const int col = wcol * 64 + no * 16 + mcol;
            const float bias = bc1[col];
            #pragma unroll
            for (int ri = 0; ri < 4; ++ri) {
                const int lrow = wrow * 16 + q * 4 + ri;
                Hs[lrow][col] = fmaxf(acc2[no][ri] + bias, 0.0f);
            }
        }
    }
    __syncthreads();

    // ---- stage 3: out = h @ Wc2 + bc2, split-bf16 MFMA (wave = one 16x16 tile)
    {
        f32x4 acc3 = (f32x4){0.f, 0.f, 0.f, 0.f};
        #pragma unroll
        for (int kp = 0; kp < 4; ++kp) {
            short8 aH, aL;
            {
                const float* p = &Hs[wrow * 16 + mcol][kp * 32 + q * 8];
                float4 v0 = *reinterpret_cast<const float4*>(p);
                float4 v1 = *reinterpret_cast<const float4*>(p + 4);
                split8(v0, v1, aH, aL);
            }
            const size_t fo = ((size_t)(kp * 2 + wcol) * 64 + lane) * 8;
            short8 bh = *reinterpret_cast<const short8*>(Wc2Sw + fo);
            short8 bo = *reinterpret_cast<const short8*>(Wc2Sw + 4096 + fo);
            acc3 = __builtin_amdgcn_mfma_f32_16x16x32_bf16(aH, bh, acc3, 0, 0, 0);
            acc3 = __builtin_amdgcn_mfma_f32_16x16x32_bf16(aL, bh, acc3, 0, 0, 0);
            acc3 = __builtin_amdgcn_mfma_f32_16x16x32_bf16(aH, bo, acc3, 0, 0, 0);
        }
        const int col = wcol * 16 + mcol;
        const float b2 = bc2[col];
        #pragma unroll
        for (int ri = 0; ri < 4; ++ri) {
            const int row = rb + wrow * 16 + q * 4 + ri;
            if (row < nrows) out[(size_t)row * C + col] = acc3[ri] + b2;
        }
    }
}

// ---------------- launch ----------------

extern "C" void kernel_launch(void* const* d_in, const int* in_sizes, int n_in,
                              void* d_out, int out_size, void* d_ws, size_t ws_size,
                              hipStream_t stream) {
    const float* node_state = (const float*)d_in[0];
    const int*   edge_index = (const int*)d_in[1];
    const int*   label_pos  = (const int*)d_in[2];
    const float* W1l = (const float*)d_in[3];
    const float* b1l = (const float*)d_in[4];
    const float* W1r = (const float*)d_in[5];
    const float* W2l = (const float*)d_in[6];
    const float* b2l = (const float*)d_in[7];
    const float* W2r = (const float*)d_in[8];
    const float* Wc1 = (const float*)d_in[9];
    const float* bc1 = (const float*)d_in[10];
    const float* Wc2 = (const float*)d_in[11];
    const float* bc2 = (const float*)d_in[12];
    float* out = (float*)d_out;

    const int* src = edge_index;       // edge_index[0]
    const int* dst = edge_index + E;   // edge_index[1]

    // workspace layout (floats first for alignment)
    char* ws = (char*)d_ws;
    float* x1c   = (float*)ws;                    ws += sizeof(float) * (size_t)N * D;
    float* bufA  = (float*)ws;                    ws += sizeof(float) * (size_t)N * D;
    unsigned short* Wsw = (unsigned short*)ws;    ws += sizeof(unsigned short) * (5 * 32768 + 8192);
    int* deg     = (int*)ws;                      ws += sizeof(int) * N;   // |
    int* flag    = (int*)ws;                      ws += sizeof(int) * N;   // | contiguous: one
    int* labflag = (int*)ws;                      ws += sizeof(int) * N;   // | memset
    int* ucnt    = (int*)ws;                      ws += sizeof(int);       // |
    float* sink  = (float*)ws;                    ws += sizeof(float);
    ws += sizeof(int) * 2;                        // pad to 16B
    int* roff    = (int*)ws;                      ws += sizeof(int) * (N + 1);
    int* cur     = (int*)ws;                      ws += sizeof(int) * N;
    int* csr_src = (int*)ws;                      ws += sizeof(int) * E;
    int* map     = (int*)ws;                      ws += sizeof(int) * N;
    int* ulist   = (int*)ws;                      ws += sizeof(int) * N;
    int* bsum    = (int*)ws;                      ws += sizeof(int) * 256;
    // bufA: mean1c [ucnt][D]; then mean2g [B][D]
    float* mean1c = bufA;
    float* mean2g = bufA;

    const int TB = 256;
    const int EB = (E + TB - 1) / TB;   // 2344 edge blocks

    // ---- preprocessing: 5 dispatches + 1 memset ----
    hipMemsetAsync(deg, 0, sizeof(int) * (3 * N + 1), stream);  // deg,flag,labflag,ucnt
    lab_k<<<(B + TB - 1) / TB, TB, 0, stream>>>(label_pos, labflag, flag, B);
    deg_swz_k<<<EB + 81 + TOUCHB, TB, 0, stream>>>(src, dst, labflag, deg, flag, E, EB,
                                                   W1l, W1r, W2l, W2r, Wc1, Wc2, Wsw,
                                                   node_state, sink);
    scan1m_k<<<2 * NB, 256, 0, stream>>>(deg, flag, bsum, N);   // per-array-aligned chunks
    scan3m_k<<<2 * NB, 256, 0, stream>>>(deg, flag, bsum, roff, cur, map, ulist, ucnt, N);
    fill_k<<<EB, TB, 0, stream>>>(src, dst, cur, csr_src, E);

    // ---- layer 1: only U rows (compact outputs) ----
    gather_mean_k<true, false><<<(N + 3) / 4, TB, 0, stream>>>(
        node_state, roff, csr_src, ulist, nullptr, ucnt, mean1c, N);
    sage_mfma_k<true, false><<<(N + 31) / 32, TB, 0, stream>>>(
        mean1c, node_state, ulist, nullptr, ucnt,
        Wsw, Wsw + 32768, b1l, x1c, N);

    // ---- layer 2 + classifier (fused; label rows; all stages MFMA) ----
    gather_mean_k<true, true><<<(B + 3) / 4, TB, 0, stream>>>(
        x1c, roff, csr_src, label_pos, map, nullptr, mean2g, B);
    sage2_cls_k<<<(B + 31) / 32, TB, 0, stream>>>(
        mean2g, x1c, label_pos, map,
        Wsw + 65536, Wsw + 98304, b2l,
        Wsw + 131072, bc1,
        Wsw + 163840, bc2, out, B);
}